// Round 1
// baseline (96.737 us; speedup 1.0000x reference)
//
#include <hip/hip_runtime.h>
#include <math.h>

// Problem constants (from reference)
constexpr int BATCH = 512;
constexpr int NC    = 10;
constexpr int RR    = 512;   // NUM_ROUTES
constexpr int CI    = 8;     // IN_CHANNELS
constexpr int CO    = 16;    // OUT_CHANNELS

// One block per (b, c) pair. 256 threads; each thread owns routes t and t+256.
// u_hat[b,c,r,o] = sum_i x[b,r,i] * route_weights[c, b, i, o]
//   (note: weight's R-slot indexed by b — that's the reference's broadcast)
__global__ __launch_bounds__(256) void caps_route_kernel(
    const float* __restrict__ x,    // (BATCH, RR, CI)
    const float* __restrict__ rw,   // (NC, RR, CI, CO)  -- RR slot indexed by b
    float* __restrict__ out)        // (BATCH, NC, CO)
{
    const int blk  = blockIdx.x;         // 0 .. BATCH*NC-1
    const int b    = blk / NC;
    const int c    = blk - b * NC;
    const int t    = threadIdx.x;        // 0..255
    const int lane = t & 63;
    const int wave = t >> 6;

    __shared__ float W[CI][CO];          // 128 floats, broadcast reads
    __shared__ float red[4][CO];         // cross-wave vector reduce
    __shared__ float sred[4];            // cross-wave scalar reduce

    // Load W = route_weights[c, b, :, :]
    if (t < CI * CO) {
        ((float*)W)[t] = rw[((size_t)c * RR + b) * (CI * CO) + t];
    }
    __syncthreads();

    // Load x rows r0 = t, r1 = t + 256 (32B contiguous per thread, coalesced)
    float xs0[CI], xs1[CI];
    {
        const float4* xp0 = (const float4*)(x + ((size_t)b * RR + t) * CI);
        const float4* xp1 = (const float4*)(x + ((size_t)b * RR + t + 256) * CI);
        float4 a0 = xp0[0], a1 = xp0[1];
        float4 b0 = xp1[0], b1 = xp1[1];
        xs0[0]=a0.x; xs0[1]=a0.y; xs0[2]=a0.z; xs0[3]=a0.w;
        xs0[4]=a1.x; xs0[5]=a1.y; xs0[6]=a1.z; xs0[7]=a1.w;
        xs1[0]=b0.x; xs1[1]=b0.y; xs1[2]=b0.z; xs1[3]=b0.w;
        xs1[4]=b1.x; xs1[5]=b1.y; xs1[6]=b1.z; xs1[7]=b1.w;
    }

    // u_hat for the two owned routes, fully in registers
    float u0[CO], u1[CO];
    #pragma unroll
    for (int o = 0; o < CO; ++o) {
        float s0 = 0.f, s1 = 0.f;
        #pragma unroll
        for (int i = 0; i < CI; ++i) {
            s0 = fmaf(xs0[i], W[i][o], s0);
            s1 = fmaf(xs1[i], W[i][o], s1);
        }
        u0[o] = s0; u1[o] = s1;
    }

    float logit0 = 0.f, logit1 = 0.f;    // b_ij for the two owned routes
    float v[CO];

    for (int iter = 0; iter < 3; ++iter) {
        // ---- softmax over all 512 routes: c_r = exp(b_r - max)/sum ----
        // block max
        float m = fmaxf(logit0, logit1);
        #pragma unroll
        for (int off = 32; off >= 1; off >>= 1)
            m = fmaxf(m, __shfl_xor(m, off, 64));
        __syncthreads();                 // protect sred/red reuse from prev iter
        if (lane == 0) sred[wave] = m;
        __syncthreads();
        m = fmaxf(fmaxf(sred[0], sred[1]), fmaxf(sred[2], sred[3]));

        float e0 = expf(logit0 - m);
        float e1 = expf(logit1 - m);
        float es = e0 + e1;
        #pragma unroll
        for (int off = 32; off >= 1; off >>= 1)
            es += __shfl_xor(es, off, 64);
        __syncthreads();
        if (lane == 0) sred[wave] = es;
        __syncthreads();
        es = (sred[0] + sred[1]) + (sred[2] + sred[3]);
        const float inv_es = 1.0f / es;
        const float c0 = e0 * inv_es;
        const float c1 = e1 * inv_es;

        // ---- s_o = sum_r c_r * u_hat[r][o] ----
        float s[CO];
        #pragma unroll
        for (int o = 0; o < CO; ++o)
            s[o] = fmaf(c0, u0[o], c1 * u1[o]);
        #pragma unroll
        for (int off = 32; off >= 1; off >>= 1) {
            #pragma unroll
            for (int o = 0; o < CO; ++o)
                s[o] += __shfl_xor(s[o], off, 64);
        }
        __syncthreads();
        if (lane == 0) {
            #pragma unroll
            for (int o = 0; o < CO; ++o) red[wave][o] = s[o];
        }
        __syncthreads();
        #pragma unroll
        for (int o = 0; o < CO; ++o)
            s[o] = (red[0][o] + red[1][o]) + (red[2][o] + red[3][o]);

        // ---- squash: v = s * (||s|| / (1 + ||s||^2)) ----
        float nsq = 0.f;
        #pragma unroll
        for (int o = 0; o < CO; ++o) nsq = fmaf(s[o], s[o], nsq);
        float nrm = sqrtf(nsq);
        float scale = nrm / (1.0f + nrm * nrm);
        #pragma unroll
        for (int o = 0; o < CO; ++o) v[o] = s[o] * scale;

        // ---- b_ij += u_hat . v (skip on last iter; unused) ----
        if (iter < 2) {
            float d0 = 0.f, d1 = 0.f;
            #pragma unroll
            for (int o = 0; o < CO; ++o) {
                d0 = fmaf(u0[o], v[o], d0);
                d1 = fmaf(u1[o], v[o], d1);
            }
            logit0 += d0;
            logit1 += d1;
        }
    }

    // ---- write v (16 floats) for this (b, c) ----
    if (t == 0) {
        float4* op = (float4*)(out + ((size_t)b * NC + c) * CO);
        op[0] = make_float4(v[0],  v[1],  v[2],  v[3]);
        op[1] = make_float4(v[4],  v[5],  v[6],  v[7]);
        op[2] = make_float4(v[8],  v[9],  v[10], v[11]);
        op[3] = make_float4(v[12], v[13], v[14], v[15]);
    }
}

extern "C" void kernel_launch(void* const* d_in, const int* in_sizes, int n_in,
                              void* d_out, int out_size, void* d_ws, size_t ws_size,
                              hipStream_t stream) {
    const float* x  = (const float*)d_in[0];   // (512, 512, 8)
    const float* rw = (const float*)d_in[1];   // (10, 512, 8, 16)
    float* out = (float*)d_out;                // (512, 10, 16)

    dim3 grid(BATCH * NC);
    dim3 block(256);
    caps_route_kernel<<<grid, block, 0, stream>>>(x, rw, out);
}

// Round 4
// 29.590 us; speedup vs baseline: 3.2692x; 3.2692x over previous
//
#include <hip/hip_runtime.h>
#include <math.h>

// Problem constants (from reference)
constexpr int BATCH = 512;
constexpr int NC    = 10;
constexpr int RR    = 512;   // NUM_ROUTES
constexpr int CI    = 8;     // IN_CHANNELS
constexpr int CO    = 16;    // OUT_CHANNELS

constexpr int TPB = 128;         // 2 waves per block
constexpr int RPT = RR / TPB;    // 4 routes per thread

// One block per (b, c). Thread t owns routes t + k*TPB, k=0..3, u_hat in regs.
// u_hat[b,c,r,o] = sum_i x[b,r,i] * route_weights[c, b, i, o]
//   (weight's R-slot indexed by b — the reference's broadcasting quirk)
__global__ __launch_bounds__(TPB) void caps_route_kernel(
    const float* __restrict__ x,    // (BATCH, RR, CI)
    const float* __restrict__ rw,   // (NC, RR, CI, CO)
    float* __restrict__ out)        // (BATCH, NC, CO)
{
    const int blk  = blockIdx.x;         // 0 .. BATCH*NC-1
    const int b    = blk / NC;
    const int c    = blk - b * NC;
    const int t    = threadIdx.x;        // 0..127
    const int lane = t & 63;
    const int wave = t >> 6;             // 0..1

    __shared__ __align__(16) float W[CI][CO];         // 512 B
    __shared__ __align__(16) float red[2][CO];        // cross-wave vector partials
    __shared__ float sred[2];                         // cross-wave denom partials

    if (t < CI * CO) {
        ((float*)W)[t] = rw[((size_t)c * RR + b) * (CI * CO) + t];
    }
    __syncthreads();

    // ---- load x rows (coalesced float4) ----
    float xs[RPT][CI];
    #pragma unroll
    for (int k = 0; k < RPT; ++k) {
        const float4* xp = (const float4*)(x + ((size_t)b * RR + t + k * TPB) * CI);
        float4 a0 = xp[0], a1 = xp[1];
        xs[k][0]=a0.x; xs[k][1]=a0.y; xs[k][2]=a0.z; xs[k][3]=a0.w;
        xs[k][4]=a1.x; xs[k][5]=a1.y; xs[k][6]=a1.z; xs[k][7]=a1.w;
    }

    // ---- u_hat for 4 owned routes, in registers ----
    float u[RPT][CO];
    #pragma unroll
    for (int k = 0; k < RPT; ++k)
        #pragma unroll
        for (int o = 0; o < CO; ++o) u[k][o] = 0.f;

    #pragma unroll
    for (int i = 0; i < CI; ++i) {
        const float4* Wrow = (const float4*)&W[i][0];
        float4 wa = Wrow[0], wb = Wrow[1], wc = Wrow[2], wd = Wrow[3];
        #pragma unroll
        for (int k = 0; k < RPT; ++k) {
            const float xv = xs[k][i];
            u[k][0]  = fmaf(xv, wa.x, u[k][0]);
            u[k][1]  = fmaf(xv, wa.y, u[k][1]);
            u[k][2]  = fmaf(xv, wa.z, u[k][2]);
            u[k][3]  = fmaf(xv, wa.w, u[k][3]);
            u[k][4]  = fmaf(xv, wb.x, u[k][4]);
            u[k][5]  = fmaf(xv, wb.y, u[k][5]);
            u[k][6]  = fmaf(xv, wb.z, u[k][6]);
            u[k][7]  = fmaf(xv, wb.w, u[k][7]);
            u[k][8]  = fmaf(xv, wc.x, u[k][8]);
            u[k][9]  = fmaf(xv, wc.y, u[k][9]);
            u[k][10] = fmaf(xv, wc.z, u[k][10]);
            u[k][11] = fmaf(xv, wc.w, u[k][11]);
            u[k][12] = fmaf(xv, wd.x, u[k][12]);
            u[k][13] = fmaf(xv, wd.y, u[k][13]);
            u[k][14] = fmaf(xv, wd.z, u[k][14]);
            u[k][15] = fmaf(xv, wd.w, u[k][15]);
        }
    }

    float logit[RPT];
    #pragma unroll
    for (int k = 0; k < RPT; ++k) logit[k] = 0.f;

    float num[CO];     // after readback+scale: s_j = (sum_r c_r u_r)
    float ks = 0.f;    // squash scale: v[o] = num[o] * ks

    for (int iter = 0; iter < 3; ++iter) {
        // ---- per-thread partials: p[o] = sum_k e_k * u[k][o], den = sum e ----
        float p[CO];
        float den_local = 0.f;
        if (iter == 0) {
            // b == 0 -> softmax uniform; fold 1/512 in at the scale step
            #pragma unroll
            for (int o = 0; o < CO; ++o)
                p[o] = (u[0][o] + u[1][o]) + (u[2][o] + u[3][o]);
        } else {
            float e[RPT];
            #pragma unroll
            for (int k = 0; k < RPT; ++k) e[k] = __expf(logit[k]);  // |logit| <~ 44, no overflow
            den_local = (e[0] + e[1]) + (e[2] + e[3]);
            #pragma unroll
            for (int o = 0; o < CO; ++o) {
                float a = fmaf(e[0], u[0][o], e[1] * u[1][o]);
                float d = fmaf(e[2], u[2][o], e[3] * u[3][o]);
                p[o] = a + d;
            }
        }

        // ---- value-split butterfly over 64 lanes (17 shuffles) ----
        // KEEP the half matching our bit, SEND the other half.
        // After 4 split stages lane holds element (lane>>2)&15;
        // final xor2/xor1 complete the 64-lane sum.
        float q1[8];
        {
            const bool hi = (lane & 32) != 0;
            #pragma unroll
            for (int k = 0; k < 8; ++k) {
                float keep = hi ? p[8 + k] : p[k];
                float send = hi ? p[k]     : p[8 + k];
                q1[k] = keep + __shfl_xor(send, 32, 64);
            }
        }
        float q2[4];
        {
            const bool hi = (lane & 16) != 0;
            #pragma unroll
            for (int k = 0; k < 4; ++k) {
                float keep = hi ? q1[4 + k] : q1[k];
                float send = hi ? q1[k]     : q1[4 + k];
                q2[k] = keep + __shfl_xor(send, 16, 64);
            }
        }
        float q3[2];
        {
            const bool hi = (lane & 8) != 0;
            #pragma unroll
            for (int k = 0; k < 2; ++k) {
                float keep = hi ? q2[2 + k] : q2[k];
                float send = hi ? q2[k]     : q2[2 + k];
                q3[k] = keep + __shfl_xor(send, 8, 64);
            }
        }
        float q4;
        {
            const bool hi = (lane & 4) != 0;
            float keep = hi ? q3[1] : q3[0];
            float send = hi ? q3[0] : q3[1];
            q4 = keep + __shfl_xor(send, 4, 64);
        }
        q4 += __shfl_xor(q4, 2, 64);
        q4 += __shfl_xor(q4, 1, 64);

        // scalar denominator butterfly (skip iter 0: den is exactly 512)
        if (iter != 0) {
            den_local += __shfl_xor(den_local, 32, 64);
            den_local += __shfl_xor(den_local, 16, 64);
            den_local += __shfl_xor(den_local,  8, 64);
            den_local += __shfl_xor(den_local,  4, 64);
            den_local += __shfl_xor(den_local,  2, 64);
            den_local += __shfl_xor(den_local,  1, 64);
        }

        __syncthreads();   // protect red/sred from previous iteration's readers
        if ((lane & 3) == 0) red[wave][lane >> 2] = q4;
        if (lane == 0)       sred[wave] = den_local;
        __syncthreads();

        // ---- read back numerator (float4) + denom ----
        {
            const float4* r0 = (const float4*)&red[0][0];
            const float4* r1 = (const float4*)&red[1][0];
            #pragma unroll
            for (int j = 0; j < 4; ++j) {
                float4 a = r0[j], d = r1[j];
                num[4*j+0] = a.x + d.x;
                num[4*j+1] = a.y + d.y;
                num[4*j+2] = a.z + d.z;
                num[4*j+3] = a.w + d.w;
            }
        }
        const float den = (iter == 0) ? (float)RR : (sred[0] + sred[1]);
        const float inv = 1.0f / den;

        // ---- SCALE FIRST (overflow-safe), then squash ----
        // s_j = num/den is a softmax-weighted mean of u rows (|s| <~ 22),
        // so nsq can't overflow; raw num^2 could hit inf in logit tails.
        #pragma unroll
        for (int o = 0; o < CO; ++o) num[o] *= inv;

        float nsq = 0.f;
        #pragma unroll
        for (int o = 0; o < CO; ++o) nsq = fmaf(num[o], num[o], nsq);
        const float nrm = sqrtf(nsq);
        ks = nrm / (1.0f + nsq);             // v[o] = num[o] * ks

        // ---- b_ij += u . v  (skip on last iter) ----
        if (iter < 2) {
            #pragma unroll
            for (int k = 0; k < RPT; ++k) {
                float d = 0.f;
                #pragma unroll
                for (int o = 0; o < CO; ++o) d = fmaf(u[k][o], num[o], d);
                logit[k] = fmaf(d, ks, logit[k]);
            }
        }
    }

    // ---- write v = num * ks for this (b, c) ----
    if (t == 0) {
        float4* op = (float4*)(out + ((size_t)b * NC + c) * CO);
        op[0] = make_float4(num[0]*ks,  num[1]*ks,  num[2]*ks,  num[3]*ks);
        op[1] = make_float4(num[4]*ks,  num[5]*ks,  num[6]*ks,  num[7]*ks);
        op[2] = make_float4(num[8]*ks,  num[9]*ks,  num[10]*ks, num[11]*ks);
        op[3] = make_float4(num[12]*ks, num[13]*ks, num[14]*ks, num[15]*ks);
    }
}

extern "C" void kernel_launch(void* const* d_in, const int* in_sizes, int n_in,
                              void* d_out, int out_size, void* d_ws, size_t ws_size,
                              hipStream_t stream) {
    const float* x  = (const float*)d_in[0];   // (512, 512, 8)
    const float* rw = (const float*)d_in[1];   // (10, 512, 8, 16)
    float* out = (float*)d_out;                // (512, 10, 16)

    dim3 grid(BATCH * NC);
    dim3 block(TPB);
    caps_route_kernel<<<grid, block, 0, stream>>>(x, rw, out);
}